// Round 10
// baseline (524.531 us; speedup 1.0000x reference)
//
#include <hip/hip_runtime.h>

// db4 synthesis filters. g1[j] = (-1)^j * g0[7-j].
__device__ constexpr float G0[8] = {
    0.23037781330885523f,  0.7148465705525415f,  0.6308807679295904f,  -0.02798376941698385f,
    -0.18703481171888114f, 0.030841381835986965f, 0.032883011666982945f, -0.010597401784997278f};
__device__ constexpr float G1[8] = {
    -0.010597401784997278f, -0.032883011666982945f, 0.030841381835986965f, 0.18703481171888114f,
    -0.02798376941698385f,  -0.6308807679295904f,   0.7148465705525415f,  -0.23037781330885523f};

// One level of 3D inverse db4 DWT, band-pair-fused separable x-pass (R9).
//
// R8 post-mortem: LDS read pipe was ~73% busy (640 scalar ds_read_b32/thread +
// 1.57e7 bank-conflict cycles) because every thread privately re-reads and
// re-computes 4-float x-windows (4x redundancy across ty). R9 computes each
// x-synthesized value ONCE, cooperatively, per band-PAIR:
//   bands (2p, 2p+1) share the y/z filters (they differ only in bit0=x), so
//   xs[dv][row][gx] = xsynth(bandL, G0x) + xsynth(bandH, G1x)  (linear)
// The y/z phase then reads aligned float2 from xs (stride-2 lanes = free
// 2-way bank aliasing): 20 ds_read_b64 per pair-thread vs 160 b32 per
// band-pair before. x-dot FLOPs shared 4-ways; y/z passes halved (4 pairs).
//
// Block tile: z-pair x WY y-ublocks x full x. Per pair: stage raw slabs of
// both bands (reg-prefetched one pair ahead, T14 split), x-pass raw->xs,
// y/z phase xs->acc. Two barriers per pair.
//
// Edge handling (all "garbage feeds only unstored outputs"):
//  - z: v=min(zb0+dv, n-1); clamped slice feeds only zo>=2, unstored when
//    z1ok is false (exactly the R8 logic, verified passing).
//  - y: top tile's rows past the volume wrap/clamp; they only enter windows
//    of threads with uy>=H, which never store (uy<H guard).
//  - volume end: rel4 clamped to n3/4-1; no straddling float4 exists since
//    chunk bases and n3 are %4==0 (n=66: (66v+4t)*66 %4==0; n=36: 36|4).
template <int n, int WY>
__global__ __launch_bounds__(256) void idwt3_sep(const float* __restrict__ low,
                                                 const float* __restrict__ highs,
                                                 float* __restrict__ out) {
  constexpr int N = 2 * n - 6;
  constexpr int H = N / 2;                  // output ublocks per axis (n-3)
  constexpr int ROWS = WY + 3;              // raw rows per z-slice
  constexpr int CHF = ROWS * n;             // floats per raw z-chunk
  constexpr int REAL4 = (CHF + 3) / 4;      // float4s per chunk (ceil)
  constexpr int CH = 4 * REAL4;             // padded chunk stride (floats)
  constexpr int TOT4 = 5 * REAL4;           // float4s per band slab
  constexpr int K = (TOT4 + 255) / 256;     // staging iters
  constexpr int W2 = 2 * H;                 // xs row width (full x output)
  constexpr int PTOT = 5 * ROWS * H;        // x-pass pair-outputs
  constexpr int KX = (PTOT + 255) / 256;    // x-pass iters
  constexpr long n3 = (long)n * n * n;
  constexpr int n3_4 = (int)(n3 / 4);

  __shared__ __align__(16) float raw[2][5 * CH];
  __shared__ __align__(16) float xs[5 * ROWS * W2];

  const int tid = threadIdx.x;
  const int zb0 = blockIdx.x * 2;           // first z-ublock of the pair
  const int yb0 = blockIdx.y * WY;          // first y-ublock of the tile
  const int b = blockIdx.z;
  const int ux = tid % H;
  const int ty = tid / H;                   // y-ublock within tile (if < WY)
  const bool z1ok = (zb0 + 1) < H;

  const float* const lowv = low + (long)b * n3;
  const float* const highv = highs + (long)b * 7 * n3;

  float4 st[2][K];                          // prefetched raw slabs (static idx)

  auto stage_load = [&](int p) {            // band pair (2p, 2p+1)
    const float* srcL = (p == 0) ? lowv : (highv + (long)(2 * p - 1) * n3);
    const float* srcH = highv + (long)(2 * p) * n3;
#pragma unroll
    for (int k = 0; k < K; ++k) {
      const int idx = tid + k * 256;
      if (idx < TOT4) {
        const int dv = idx / REAL4;               // const divisor
        const int c = idx - dv * REAL4;
        const int v = min(zb0 + dv, n - 1);       // z-edge clamp
        int rel4 = ((v * n + yb0) * n) / 4 + c;   // chunk base %4==0
        rel4 = min(rel4, n3_4 - 1);               // volume-end clamp
        st[0][k] = *reinterpret_cast<const float4*>(srcL + 4 * (long)rel4);
        st[1][k] = *reinterpret_cast<const float4*>(srcH + 4 * (long)rel4);
      }
    }
  };

  float acc[4][2][2] = {};                  // [zo][py][px]

  stage_load(0);                            // prologue

#pragma unroll 1
  for (int p = 0; p < 4; ++p) {
    // commit prefetched slabs -> LDS (raw readers of pair p-1 finished before
    // the p-1 loop's second barrier; xs readers finish before the barrier below)
#pragma unroll
    for (int k = 0; k < K; ++k) {
      const int idx = tid + k * 256;
      if (idx < TOT4) {
        *reinterpret_cast<float4*>(&raw[0][4 * idx]) = st[0][k];
        *reinterpret_cast<float4*>(&raw[1][4 * idx]) = st[1][k];
      }
    }
    __syncthreads();                        // raw visible; xs safe to overwrite
    if (p < 3) stage_load(p + 1);           // next pair's loads fly under compute

    // x-pass: each pair-output (dv,row,u) -> xs[dv][row][2u..2u+1], computed once.
#pragma unroll
    for (int k = 0; k < KX; ++k) {
      const int idx = tid + k * 256;
      if (idx < PTOT) {
        const int dv = idx / (ROWS * H);    // const divisors
        const int r = idx - dv * (ROWS * H);
        const int row = r / H;
        const int u = r - row * H;
        const int base = dv * CH + row * n + u;
        const float l0 = raw[0][base],     l1 = raw[0][base + 1],
                    l2 = raw[0][base + 2], l3 = raw[0][base + 3];
        const float h0 = raw[1][base],     h1 = raw[1][base + 1],
                    h2 = raw[1][base + 2], h3 = raw[1][base + 3];
        // gx=2u+px: sum_j wl[j]*G0[px+6-2j] + wh[j]*G1[px+6-2j]
        float x0 = l0 * G0[6] + l1 * G0[4] + l2 * G0[2] + l3 * G0[0]
                 + h0 * G1[6] + h1 * G1[4] + h2 * G1[2] + h3 * G1[0];
        float x1 = l0 * G0[7] + l1 * G0[5] + l2 * G0[3] + l3 * G0[1]
                 + h0 * G1[7] + h1 * G1[5] + h2 * G1[3] + h3 * G1[1];
        *reinterpret_cast<float2*>(&xs[(dv * ROWS + row) * W2 + 2 * u]) =
            make_float2(x0, x1);
      }
    }
    __syncthreads();                        // xs visible

    // y/z phase: read aligned float2 pairs from xs, contract y then z.
    if (ty < WY) {
      const float* Gy = (p & 1) ? G1 : G0;  // pair shares y/z filters
      const float* Gz = (p & 2) ? G1 : G0;
#pragma unroll
      for (int dv = 0; dv < 5; ++dv) {
        float d[4][2];
#pragma unroll
        for (int du = 0; du < 4; ++du) {
          const float2 v2 = *reinterpret_cast<const float2*>(
              &xs[(dv * ROWS + ty + du) * W2 + 2 * ux]);
          d[du][0] = v2.x;
          d[du][1] = v2.y;
        }
        float ey[2][2];
#pragma unroll
        for (int py = 0; py < 2; ++py) {
#pragma unroll
          for (int px = 0; px < 2; ++px) {
            float s = d[0][px] * Gy[py + 6];
            s = fmaf(d[1][px], Gy[py + 4], s);
            s = fmaf(d[2][px], Gy[py + 2], s);
            s = fmaf(d[3][px], Gy[py + 0], s);
            ey[py][px] = s;
          }
        }
        // z-accumulate: slice dv feeds zo with mz=(zo>>1)+3-dv in [0,3]
#pragma unroll
        for (int zo = 0; zo < 4; ++zo) {
          const int mz = (zo >> 1) + 3 - dv;
          if (mz >= 0 && mz <= 3) {
            const float w = Gz[(zo & 1) + 2 * mz];
#pragma unroll
            for (int py = 0; py < 2; ++py)
#pragma unroll
              for (int px = 0; px < 2; ++px)
                acc[zo][py][px] = fmaf(ey[py][px], w, acc[zo][py][px]);
          }
        }
      }
    }
  }

  // stores
  const int uy = yb0 + ty;
  if (ty < WY && uy < H) {
    const long N3 = (long)N * N * N;
    float* obase = out + (long)b * N3 + 2 * ux;
#pragma unroll
    for (int zo = 0; zo < 4; ++zo) {
      if (zo >= 2 && !z1ok) continue;
      const int gz = 2 * zb0 + zo;
#pragma unroll
      for (int py = 0; py < 2; ++py) {
        const int gy = 2 * uy + py;
        float2 vv = make_float2(acc[zo][py][0], acc[zo][py][1]);
        *reinterpret_cast<float2*>(obase + ((long)gz * N + gy) * N) = vv;
      }
    }
  }
}

extern "C" void kernel_launch(void* const* d_in, const int* in_sizes, int n_in,
                              void* d_out, int out_size, void* d_ws, size_t ws_size,
                              hipStream_t stream) {
  // Identify inputs BY SIZE (element counts — confirmed in prior session):
  //   yl  (2,8,36^3)    =   746,496
  //   yh0 (2,8,7,66^3)  = 32,199,552
  //   yh1 (2,8,7,36^3)  =  5,225,472
  const float* yl  = nullptr;
  const float* yh0 = nullptr;
  const float* yh1 = nullptr;
  for (int i = 0; i < n_in; ++i) {
    if (in_sizes[i] == 746496)        yl  = (const float*)d_in[i];
    else if (in_sizes[i] == 32199552) yh0 = (const float*)d_in[i];
    else if (in_sizes[i] == 5225472)  yh1 = (const float*)d_in[i];
  }
  if (!yl || !yh0 || !yh1) {
    yl  = (const float*)d_in[0];
    yh0 = (const float*)d_in[1];
    yh1 = (const float*)d_in[2];
  }
  float* out = (float*)d_out;      // fp32 output (verified prior session)
  float* ll  = (float*)d_ws;       // (16,66^3) fp32 = 18.4 MB inter-level buffer

  // Level 1: (36 -> 66). H=33: 17 zpairs x 11 ytiles (WY=3) x 16 vols = 2992
  // blocks (was 1360 -- level-1 was grid-starved at 5.3 waves/SIMD).
  idwt3_sep<36, 3><<<dim3(17, 11, 16), 256, 0, stream>>>(yl, yh1, ll);

  // Level 2: (66 -> 126). H=63: 32 zpairs x 16 ytiles (WY=4) x 16 vols.
  idwt3_sep<66, 4><<<dim3(32, 16, 16), 256, 0, stream>>>(ll, yh0, out);
}

// Round 15
// 419.739 us; speedup vs baseline: 1.2497x; 1.2497x over previous
//
#include <hip/hip_runtime.h>

// db4 synthesis filters. g1[j] = (-1)^j * g0[7-j].
__device__ constexpr float G0[8] = {
    0.23037781330885523f,  0.7148465705525415f,  0.6308807679295904f,  -0.02798376941698385f,
    -0.18703481171888114f, 0.030841381835986965f, 0.032883011666982945f, -0.010597401784997278f};
__device__ constexpr float G1[8] = {
    -0.010597401784997278f, -0.032883011666982945f, 0.030841381835986965f, 0.18703481171888114f,
    -0.02798376941698385f,  -0.6308807679295904f,   0.7148465705525415f,  -0.23037781330885523f};

// R10: z-sliding 3D inverse db4 synthesis. Block = (z-segment, y-tile, volume).
// Stream source slices v = zb_lo .. zb_hi+2; per slice:
//   stage (8 bands, flat ROWS*n run, float4, reg-prefetched 1 slice ahead)
//   x-synth per band-PAIR once into xs[dv&1]  (R9's verified formula)
//   y-contract (R4's verified formula) -> ey[pair][py][px]
//   z-scatter: pend[j][py][px] += Gz_pair[j] * ey,  j = gz-2v+6  (weight index
//     IS j: gz=2v-6+j -> mz=(j>>1), pz=j&1 -> Gz[pz+2mz]=Gz[j])
//   after slice v, rows gz=2v-6,2v-5 (zb=v-3) are complete -> store, shift ring.
// Every slice is staged & x-synthesized ONCE (was 2.5x z-redundant); per-output
// fma 152->~82, st prefetch only K<=4 float4 (kills R8/R9's 281-613MB write-
// amplification suspect = spilled st). Two barriers/slice; xs double-buffered,
// raw single-buffered (commit at iter top is safe: xsynth readers of the prev
// slice all passed the prev bottom barrier).
//
// Edge handling (all "garbage feeds only unstored outputs"):
//  - v range [zb_lo, zb_hi+2], zb_hi<=H=n-3 -> v<=n-1: NO z clamp needed.
//  - y: flat run rows yb0..yb0+ROWS-1 may extend past row n-1 into the next
//    slice's rows (in-bounds global garbage) -> feeds only uy>=H (act=false).
//  - volume end: rel4 clamped to n3/4-1 (top tile of last slice only); flat
//    base ((v*n+yb0)*n)%4==0 proven: n=66,yb0=4t: 4356v+264t; n=36: 36|base.
template <int n, int WY, int ZSEG>
__device__ __forceinline__ void idwt3_slide_body(const float* __restrict__ low,
                                                 const float* __restrict__ highs,
                                                 float* __restrict__ out) {
  constexpr int N = 2 * n - 6;
  constexpr int H = n - 3;                  // output ublocks per axis
  constexpr int ROWS = WY + 3;              // y rows per staged slice
  constexpr int SLF = ROWS * n;             // floats per band-slice region
  constexpr int REAL4 = (SLF + 3) / 4;      // float4s per band-slice
  constexpr int RB = 4 * REAL4;             // raw band stride (floats)
  constexpr int K = (8 * REAL4 + 255) / 256;
  constexpr int W2 = 2 * H;                 // xs row width
  constexpr int XT = 4 * ROWS * H;          // x-synth outs per slice
  constexpr int KX = (XT + 255) / 256;
  constexpr long n3 = (long)n * n * n;
  constexpr int n3_4 = (int)(n3 / 4);

  __shared__ __align__(16) float raw[8 * RB];
  __shared__ __align__(16) float xs[2][4 * ROWS * W2];

  const int tid = threadIdx.x;
  const int zb_lo = blockIdx.x * ZSEG;
  const int zb_hi = min(zb_lo + ZSEG, H);
  const int yb0 = blockIdx.y * WY;
  const int b = blockIdx.z;
  const int ux = tid % H;
  const int ty = tid / H;
  const int uy = yb0 + ty;
  const bool act = (ty < WY) && (uy < H);

  const float* const lowv = low + (long)b * n3;
  const float* const highv = highs + (long)b * 7 * n3;

  const int nsl = (zb_hi - zb_lo) + 3;      // slices to process

  float4 st[K];
  auto stage_load = [&](int v) {
    const int fb4 = ((v * n + yb0) * n) >> 2;     // %4==0 proven above
#pragma unroll
    for (int k = 0; k < K; ++k) {
      const int idx = tid + k * 256;
      if (idx < 8 * REAL4) {
        const int band = idx / REAL4;             // const divisor
        const int c = idx - band * REAL4;
        const float* src = (band == 0) ? lowv : (highv + (long)(band - 1) * n3);
        const int rel4 = min(fb4 + c, n3_4 - 1);  // volume-end clamp
        st[k] = *reinterpret_cast<const float4*>(src + 4 * (long)rel4);
      }
    }
  };

  float pend[8][2][2] = {};                 // ring: [j][py][px], gz = 2v-6+j

  stage_load(zb_lo);

#pragma unroll 1
  for (int i = 0; i <= nsl; ++i) {
    if (i < nsl) {
      // commit st -> raw (everyone passed prev bottom barrier -> raw free)
#pragma unroll
      for (int k = 0; k < K; ++k) {
        const int idx = tid + k * 256;
        if (idx < 8 * REAL4) {
          const int band = idx / REAL4;
          const int c = idx - band * REAL4;
          *reinterpret_cast<float4*>(&raw[band * RB + 4 * c]) = st[k];
        }
      }
    }
    __syncthreads();                        // raw visible; xs[i&1] free
    if (i + 1 < nsl) stage_load(zb_lo + i + 1);   // fly under compute (T14)

    if (i < nsl) {
      // x-synth slice v = zb_lo+i into xs[i&1]; each pair-out computed once.
      float* xd = xs[i & 1];
#pragma unroll
      for (int k = 0; k < KX; ++k) {
        const int idx = tid + k * 256;
        if (idx < XT) {
          const int p = idx / (ROWS * H);   // const divisors
          const int r = idx - p * (ROWS * H);
          const int row = r / H;
          const int u = r - row * H;
          const float* rl = &raw[(2 * p) * RB + row * n + u];
          const float* rh = rl + RB;
          const float l0 = rl[0], l1 = rl[1], l2 = rl[2], l3 = rl[3];
          const float h0 = rh[0], h1 = rh[1], h2 = rh[2], h3 = rh[3];
          // gx=2u+px: sum_c l_c*G0[px+6-2c] + h_c*G1[px+6-2c]  (R9-verified)
          const float x0 = l0 * G0[6] + l1 * G0[4] + l2 * G0[2] + l3 * G0[0]
                         + h0 * G1[6] + h1 * G1[4] + h2 * G1[2] + h3 * G1[0];
          const float x1 = l0 * G0[7] + l1 * G0[5] + l2 * G0[3] + l3 * G0[1]
                         + h0 * G1[7] + h1 * G1[5] + h2 * G1[3] + h3 * G1[1];
          *reinterpret_cast<float2*>(&xd[(p * ROWS + row) * W2 + 2 * u]) =
              make_float2(x0, x1);
        }
      }
    }

    if (i > 0 && act) {
      // consume slice w = zb_lo+i-1 from xs[(i-1)&1]
      const int w = zb_lo + i - 1;
      const float* xsrc = xs[(i & 1) ^ 1];
#pragma unroll
      for (int p = 0; p < 4; ++p) {
        const float* Gy = (p & 1) ? G1 : G0;
        const float* Gz = (p & 2) ? G1 : G0;
        float d[4][2];
#pragma unroll
        for (int du = 0; du < 4; ++du) {
          const float2 v2 = *reinterpret_cast<const float2*>(
              &xsrc[(p * ROWS + ty + du) * W2 + 2 * ux]);
          d[du][0] = v2.x;
          d[du][1] = v2.y;
        }
        float ey[2][2];
#pragma unroll
        for (int py = 0; py < 2; ++py) {
#pragma unroll
          for (int px = 0; px < 2; ++px) {
            float s = d[0][px] * Gy[py + 6];            // R4-verified y form
            s = fmaf(d[1][px], Gy[py + 4], s);
            s = fmaf(d[2][px], Gy[py + 2], s);
            s = fmaf(d[3][px], Gy[py + 0], s);
            ey[py][px] = s;
          }
        }
#pragma unroll
        for (int j = 0; j < 8; ++j) {
          const float wz = Gz[j];                       // j IS the filter index
#pragma unroll
          for (int py = 0; py < 2; ++py)
#pragma unroll
            for (int px = 0; px < 2; ++px)
              pend[j][py][px] = fmaf(ey[py][px], wz, pend[j][py][px]);
        }
      }
      // rows zb_c = w-3 complete -> store (if in this segment), shift ring by 2
      const int zb_c = w - 3;
      if (zb_c >= zb_lo && zb_c < zb_hi) {
        const long N3 = (long)N * N * N;
        float* obase = out + (long)b * N3 + 2 * ux;
#pragma unroll
        for (int pz = 0; pz < 2; ++pz) {
          const int gz = 2 * zb_c + pz;
#pragma unroll
          for (int py = 0; py < 2; ++py) {
            const int gy = 2 * uy + py;
            *reinterpret_cast<float2*>(obase + ((long)gz * N + gy) * N) =
                make_float2(pend[pz][py][0], pend[pz][py][1]);
          }
        }
      }
#pragma unroll
      for (int j = 0; j < 6; ++j)
#pragma unroll
        for (int py = 0; py < 2; ++py)
#pragma unroll
          for (int px = 0; px < 2; ++px)
            pend[j][py][px] = pend[j + 2][py][px];
#pragma unroll
      for (int py = 0; py < 2; ++py)
#pragma unroll
        for (int px = 0; px < 2; ++px) {
          pend[6][py][px] = 0.0f;
          pend[7][py][px] = 0.0f;
        }
    }
    __syncthreads();                        // xs[(i&1)^1] free for next xsynth
  }
}

// Separate symbols per level so rocprof finally shows where the ~200us
// residual lives (template instantiations share one demangled name).
__global__ __launch_bounds__(256) void idwt3_s_lvl1(const float* __restrict__ low,
                                                    const float* __restrict__ highs,
                                                    float* __restrict__ out) {
  idwt3_slide_body<36, 7, 4>(low, highs, out);
}
__global__ __launch_bounds__(256) void idwt3_s_lvl2(const float* __restrict__ low,
                                                    const float* __restrict__ highs,
                                                    float* __restrict__ out) {
  idwt3_slide_body<66, 4, 8>(low, highs, out);
}

extern "C" void kernel_launch(void* const* d_in, const int* in_sizes, int n_in,
                              void* d_out, int out_size, void* d_ws, size_t ws_size,
                              hipStream_t stream) {
  // Identify inputs BY SIZE (element counts — confirmed in prior session):
  //   yl  (2,8,36^3)    =   746,496
  //   yh0 (2,8,7,66^3)  = 32,199,552
  //   yh1 (2,8,7,36^3)  =  5,225,472
  const float* yl  = nullptr;
  const float* yh0 = nullptr;
  const float* yh1 = nullptr;
  for (int i = 0; i < n_in; ++i) {
    if (in_sizes[i] == 746496)        yl  = (const float*)d_in[i];
    else if (in_sizes[i] == 32199552) yh0 = (const float*)d_in[i];
    else if (in_sizes[i] == 5225472)  yh1 = (const float*)d_in[i];
  }
  if (!yl || !yh0 || !yh1) {
    yl  = (const float*)d_in[0];
    yh0 = (const float*)d_in[1];
    yh1 = (const float*)d_in[2];
  }
  float* out = (float*)d_out;      // fp32 output (verified prior session)
  float* ll  = (float*)d_ws;       // (16,66^3) fp32 = 18.4 MB inter-level buffer

  // Level 1: (36 -> 66). H=33: 9 zsegs(ZSEG=4) x 5 ytiles(WY=7) x 16 vols.
  idwt3_s_lvl1<<<dim3(9, 5, 16), 256, 0, stream>>>(yl, yh1, ll);

  // Level 2: (66 -> 126). H=63: 8 zsegs(ZSEG=8) x 16 ytiles(WY=4) x 16 vols.
  idwt3_s_lvl2<<<dim3(8, 16, 16), 256, 0, stream>>>(ll, yh0, out);
}